// Round 3
// baseline (761.123 us; speedup 1.0000x reference)
//
#include <hip/hip_runtime.h>
#include <hip/hip_bf16.h>

#define B_   16
#define CIN  512
#define COUT 512
#define H_   64
#define W_   64
#define HW   4096
#define SDIM 32

typedef __attribute__((ext_vector_type(4))) float f32x4;
typedef __attribute__((ext_vector_type(8))) short bf16x8;

__device__ __forceinline__ unsigned short f2bf(float f) {
  __hip_bfloat16 h = __float2bfloat16(f);
  return *reinterpret_cast<unsigned short*>(&h);
}
__device__ __forceinline__ float bf2f(unsigned short u) {
  unsigned int v = ((unsigned int)u) << 16;
  return __uint_as_float(v);
}

__device__ __forceinline__ void gload_lds16(const void* g, void* l) {
  __builtin_amdgcn_global_load_lds(
      (const __attribute__((address_space(1))) unsigned int*)g,
      (__attribute__((address_space(3))) unsigned int*)l, 16, 0, 0);
}

// ---------------- kernel 1: modulated + demodulated weights (bf16) ----------
__global__ __launch_bounds__(256) void modw_kernel(
    const float* __restrict__ style, const float* __restrict__ conv_w,
    const float* __restrict__ mod_w, const float* __restrict__ mod_b,
    __hip_bfloat16* __restrict__ wmod) {
  const int o = blockIdx.x, b = blockIdx.y, t = threadIdx.x;
  __shared__ float sty[SDIM];
  __shared__ float red[4];
  if (t < SDIM) sty[t] = style[b * SDIM + t];
  __syncthreads();
  float wv[2];
  float ssq = 0.f;
#pragma unroll
  for (int hh = 0; hh < 2; ++hh) {
    int ci = t + hh * 256;
    const float4* mw = (const float4*)(mod_w + (size_t)ci * SDIM);
    float s = mod_b[ci];
#pragma unroll
    for (int q = 0; q < SDIM / 4; ++q) {
      float4 m4 = mw[q];
      s += m4.x * sty[q * 4 + 0] + m4.y * sty[q * 4 + 1] +
           m4.z * sty[q * 4 + 2] + m4.w * sty[q * 4 + 3];
    }
    float w0 = conv_w[(size_t)o * CIN + ci] * s;
    wv[hh] = w0;
    ssq += w0 * w0;
  }
#pragma unroll
  for (int off = 32; off > 0; off >>= 1) ssq += __shfl_down(ssq, off, 64);
  if ((t & 63) == 0) red[t >> 6] = ssq;
  __syncthreads();
  float dm = rsqrtf(red[0] + red[1] + red[2] + red[3] + 1e-8f);
#pragma unroll
  for (int hh = 0; hh < 2; ++hh) {
    int ci = t + hh * 256;
    wmod[((size_t)b * COUT + o) * CIN + ci] = __float2bfloat16(wv[hh] * dm);
  }
}

// ---------------- kernel 2: x [cin][p] fp32 -> xT [p][cin] bf16 -------------
__global__ __launch_bounds__(256) void xpose_kernel(const float* __restrict__ x,
                                                    __hip_bfloat16* __restrict__ xT) {
  const int pt = blockIdx.x, ct = blockIdx.y, b = blockIdx.z;
  const int t = threadIdx.x;
  __shared__ float tile[64][65];
  const int p0 = pt * 64, c0 = ct * 64;
  const float* xb = x + (size_t)b * CIN * HW;
  const int row = t >> 4;          // 0..15
  const int col4 = (t & 15) * 4;   // 0..60
#pragma unroll
  for (int i = 0; i < 4; ++i) {
    int r = row + i * 16;
    float4 v = *(const float4*)(xb + (size_t)(c0 + r) * HW + p0 + col4);
    tile[r][col4 + 0] = v.x;
    tile[r][col4 + 1] = v.y;
    tile[r][col4 + 2] = v.z;
    tile[r][col4 + 3] = v.w;
  }
  __syncthreads();
  unsigned short* xTb = (unsigned short*)xT + (size_t)b * HW * CIN;
#pragma unroll
  for (int i = 0; i < 4; ++i) {
    int pr = row + i * 16;
    ushort4 u;
    u.x = f2bf(tile[col4 + 0][pr]);
    u.y = f2bf(tile[col4 + 1][pr]);
    u.z = f2bf(tile[col4 + 2][pr]);
    u.w = f2bf(tile[col4 + 3][pr]);
    *(ushort4*)(xTb + (size_t)(p0 + pr) * CIN + c0 + col4) = u;
  }
}

// ---------------- kernel 3: per-sample GEMM y = wmod @ x (bf16 MFMA) --------
// y[cout][p] = sum_k wmod[cout][k] * xT[p][k]   (both K-contiguous, m97-style)
__global__ __launch_bounds__(256) void gemm_kernel(
    const __hip_bfloat16* __restrict__ wmod,
    const __hip_bfloat16* __restrict__ xT,
    __hip_bfloat16* __restrict__ y) {
  __shared__ __hip_bfloat16 lsA[128 * 32];
  __shared__ __hip_bfloat16 lsB[128 * 32];
  const int nt = blockIdx.x, mt = blockIdx.y, b = blockIdx.z;
  const int tid = threadIdx.x;
  const int wave = tid >> 6, lane = tid & 63;
  const int m0 = mt * 128, n0 = nt * 128;
  const __hip_bfloat16* Ag = wmod + ((size_t)b * COUT + m0) * CIN;
  const __hip_bfloat16* Bg = xT + ((size_t)b * HW + n0) * CIN;
  f32x4 acc[4][4] = {};
  const int wm = wave >> 1, wn = wave & 1;
  const int srow = lane >> 2;        // 0..15
  const int skof = (lane & 3) * 8;   // k element offset within 32
  const int fr = lane & 15, fk = (lane >> 4) * 8;

  for (int kk = 0; kk < CIN; kk += 32) {
#pragma unroll
    for (int i = 0; i < 2; ++i) {
      int r = wave * 32 + i * 16 + srow;
      gload_lds16(Ag + (size_t)r * CIN + kk + skof,
                  (void*)(lsA + (wave * 32 + i * 16) * 32));
      gload_lds16(Bg + (size_t)r * CIN + kk + skof,
                  (void*)(lsB + (wave * 32 + i * 16) * 32));
    }
    __syncthreads();
    bf16x8 av[4], bv[4];
#pragma unroll
    for (int m = 0; m < 4; ++m)
      av[m] = *(const bf16x8*)(lsA + (wm * 64 + m * 16 + fr) * 32 + fk);
#pragma unroll
    for (int n = 0; n < 4; ++n)
      bv[n] = *(const bf16x8*)(lsB + (wn * 64 + n * 16 + fr) * 32 + fk);
#pragma unroll
    for (int m = 0; m < 4; ++m)
#pragma unroll
      for (int n = 0; n < 4; ++n)
        acc[m][n] = __builtin_amdgcn_mfma_f32_16x16x32_bf16(av[m], bv[n], acc[m][n], 0, 0, 0);
    __syncthreads();
  }

  __hip_bfloat16* yb = y + (size_t)b * COUT * HW;
  const int rr = (lane >> 4) * 4;
#pragma unroll
  for (int m = 0; m < 4; ++m) {
#pragma unroll
    for (int n = 0; n < 4; ++n) {
#pragma unroll
      for (int r = 0; r < 4; ++r) {
        int row = m0 + wm * 64 + m * 16 + rr + r;
        int col = n0 + wn * 64 + n * 16 + fr;
        yb[(size_t)row * HW + col] = __float2bfloat16(acc[m][n][r]);
      }
    }
  }
}

// ---------------- kernel 4: bilinear x2 upsample (half-pixel, edge clamp) ---
__global__ __launch_bounds__(256) void upsample_kernel(const __hip_bfloat16* __restrict__ y,
                                                       float* __restrict__ out) {
  const int c = blockIdx.x, b = blockIdx.y;
  const int t = threadIdx.x;
  __shared__ unsigned short Y[HW];  // one 64x64 bf16 image, 8KB
  const uint4* yb = (const uint4*)((const unsigned short*)y + ((size_t)b * COUT + c) * HW);
  ((uint4*)Y)[t] = yb[t];
  ((uint4*)Y)[t + 256] = yb[t + 256];
  __syncthreads();
  float* ob = out + ((size_t)b * COUT + c) * 128 * 128;
#pragma unroll
  for (int it = 0; it < 16; ++it) {
    int q = t + it * 256;      // 0..4095 output float4 index
    int i = q >> 5;            // out row 0..127
    int j0 = (q & 31) * 4;     // out col, multiple of 4
    int k = i >> 1;
    int r0, r1;
    float wr0, wr1;
    if (i & 1) { r0 = k; r1 = (k + 1 < 64) ? k + 1 : 63; wr0 = 0.75f; wr1 = 0.25f; }
    else       { r0 = (k - 1 >= 0) ? k - 1 : 0; r1 = k; wr0 = 0.25f; wr1 = 0.75f; }
    int m = j0 >> 1;
    int cm1 = (m - 1 >= 0) ? m - 1 : 0;
    int c1 = (m + 1 < 64) ? m + 1 : 63;
    int c2 = (m + 2 < 64) ? m + 2 : 63;
    const unsigned short* Yr0 = Y + r0 * 64;
    const unsigned short* Yr1 = Y + r1 * 64;
    float g0 = wr0 * bf2f(Yr0[cm1]) + wr1 * bf2f(Yr1[cm1]);
    float g1 = wr0 * bf2f(Yr0[m])   + wr1 * bf2f(Yr1[m]);
    float g2 = wr0 * bf2f(Yr0[c1])  + wr1 * bf2f(Yr1[c1]);
    float g3 = wr0 * bf2f(Yr0[c2])  + wr1 * bf2f(Yr1[c2]);
    float4 o;
    o.x = 0.25f * g0 + 0.75f * g1;
    o.y = 0.75f * g1 + 0.25f * g2;
    o.z = 0.25f * g1 + 0.75f * g2;
    o.w = 0.75f * g2 + 0.25f * g3;
    *(float4*)(ob + (size_t)i * 128 + j0) = o;
  }
}

extern "C" void kernel_launch(void* const* d_in, const int* in_sizes, int n_in,
                              void* d_out, int out_size, void* d_ws, size_t ws_size,
                              hipStream_t stream) {
  const float* x      = (const float*)d_in[0];
  const float* style  = (const float*)d_in[1];
  const float* conv_w = (const float*)d_in[2];
  const float* mod_w  = (const float*)d_in[3];
  const float* mod_b  = (const float*)d_in[4];
  float* out = (float*)d_out;

  // workspace layout: wmod 8 MiB | xT 64 MiB | y 64 MiB  (136 MiB total)
  __hip_bfloat16* wmod = (__hip_bfloat16*)d_ws;
  __hip_bfloat16* xT   = (__hip_bfloat16*)((char*)d_ws + ((size_t)8 << 20));
  __hip_bfloat16* y    = (__hip_bfloat16*)((char*)d_ws + ((size_t)72 << 20));

  modw_kernel<<<dim3(COUT, B_), 256, 0, stream>>>(style, conv_w, mod_w, mod_b, wmod);
  xpose_kernel<<<dim3(64, 8, B_), 256, 0, stream>>>(x, xT);
  gemm_kernel<<<dim3(32, 4, B_), 256, 0, stream>>>(wmod, xT, y);
  upsample_kernel<<<dim3(COUT, B_), 256, 0, stream>>>(y, out);
}